// Round 1
// baseline (6493.279 us; speedup 1.0000x reference)
//
#include <hip/hip_runtime.h>
#include <hip/hip_bf16.h>

#define T_STEPS 2048
#define NB      64
#define IN_DIM  300
#define HID     512

typedef __attribute__((ext_vector_type(8))) short short8;   // 8 bf16 (4 VGPR)
typedef __attribute__((ext_vector_type(4))) float f32x4;    // MFMA accumulator

static __device__ __forceinline__ unsigned short f2bf(float x) {
    unsigned int u = __float_as_uint(x);
    u = u + 0x7FFFu + ((u >> 16) & 1u);          // round-to-nearest-even
    return (unsigned short)(u >> 16);
}
static __device__ __forceinline__ float bf2f(unsigned short h) {
    return __uint_as_float(((unsigned int)h) << 16);
}

// ---------------------------------------------------------------------------
// Kernel 1: U[t*64+b][j] = bf16( x_t[b] . W_ih[j] + b_ih[j] + b_hh[j] )
// M=131072 rows, N=512, K=300 (padded to 320). 64x64 tile per 256-thr block,
// K staged in two 160-wide halves (2x20KB LDS). XOR-swizzled LDS tiles.
// ---------------------------------------------------------------------------
__global__ __launch_bounds__(256, 4) void u_gemm(
    const float* __restrict__ X, const float* __restrict__ Wih,
    const float* __restrict__ bih, const float* __restrict__ bhh,
    unsigned short* __restrict__ U)
{
    __shared__ unsigned short As[64 * 160];
    __shared__ unsigned short Bs[64 * 160];
    const int tid = threadIdx.x;
    const int m0 = (blockIdx.x >> 3) * 64, n0 = (blockIdx.x & 7) * 64;
    const int w = tid >> 6, l = tid & 63;

    const f32x4 zv = {0.f, 0.f, 0.f, 0.f};
    f32x4 acc00 = zv, acc01 = zv, acc10 = zv, acc11 = zv;

    for (int kh = 0; kh < 2; ++kh) {
        const int kbase = kh * 160;
        __syncthreads();
        for (int i = tid; i < 64 * 40; i += 256) {
            const int r = i / 40, q = i - r * 40;
            const int kg = kbase + q * 4;
            unsigned int a0 = 0, a1 = 0, b0 = 0, b1 = 0;
            if (kg + 4 <= IN_DIM) {
                const float4 v = *reinterpret_cast<const float4*>(X + (size_t)(m0 + r) * IN_DIM + kg);
                a0 = (unsigned)f2bf(v.x) | ((unsigned)f2bf(v.y) << 16);
                a1 = (unsigned)f2bf(v.z) | ((unsigned)f2bf(v.w) << 16);
                const float4 u = *reinterpret_cast<const float4*>(Wih + (size_t)(n0 + r) * IN_DIM + kg);
                b0 = (unsigned)f2bf(u.x) | ((unsigned)f2bf(u.y) << 16);
                b1 = (unsigned)f2bf(u.z) | ((unsigned)f2bf(u.w) << 16);
            }
            int byte = r * 320 + q * 8; byte ^= ((r & 7) << 4);
            *reinterpret_cast<uint2*>(reinterpret_cast<char*>(As) + byte) = make_uint2(a0, a1);
            *reinterpret_cast<uint2*>(reinterpret_cast<char*>(Bs) + byte) = make_uint2(b0, b1);
        }
        __syncthreads();
        #pragma unroll
        for (int kc = 0; kc < 5; ++kc) {
            const int koff = kc * 64 + (l >> 4) * 16;
            short8 a[2], b[2];
            #pragma unroll
            for (int mt = 0; mt < 2; ++mt) {
                const int row = (w >> 1) * 32 + mt * 16 + (l & 15);
                int abyte = row * 320 + koff; abyte ^= ((row & 7) << 4);
                a[mt] = *reinterpret_cast<const short8*>(reinterpret_cast<const char*>(As) + abyte);
                const int jrow = (w & 1) * 32 + mt * 16 + (l & 15);
                int bbyte = jrow * 320 + koff; bbyte ^= ((jrow & 7) << 4);
                b[mt] = *reinterpret_cast<const short8*>(reinterpret_cast<const char*>(Bs) + bbyte);
            }
            acc00 = __builtin_amdgcn_mfma_f32_16x16x32_bf16(a[0], b[0], acc00, 0, 0, 0);
            acc01 = __builtin_amdgcn_mfma_f32_16x16x32_bf16(a[0], b[1], acc01, 0, 0, 0);
            acc10 = __builtin_amdgcn_mfma_f32_16x16x32_bf16(a[1], b[0], acc10, 0, 0, 0);
            acc11 = __builtin_amdgcn_mfma_f32_16x16x32_bf16(a[1], b[1], acc11, 0, 0, 0);
        }
    }
    #pragma unroll
    for (int nt = 0; nt < 2; ++nt) {
        const int col = n0 + (w & 1) * 32 + nt * 16 + (l & 15);
        const float bias = bih[col] + bhh[col];
        #pragma unroll
        for (int mt = 0; mt < 2; ++mt) {
            const f32x4 acc = (mt == 0) ? (nt == 0 ? acc00 : acc01)
                                        : (nt == 0 ? acc10 : acc11);
            const int rbase = m0 + (w >> 1) * 32 + mt * 16 + (l >> 4) * 4;
            #pragma unroll
            for (int r = 0; r < 4; ++r)
                U[(size_t)(rbase + r) * HID + col] = f2bf(acc[r] + bias);
        }
    }
}

// ---------------------------------------------------------------------------
// Kernel 2: recurrence. 4 groups x 16 batches; group g = blocks {g, g+8}
// (same XCD by round-robin heuristic; correctness via agent-scope atomics).
// Each block: stationary bf16 W_hh fragments for 256 cols (128 VGPR/thread),
// 256 MFMA/step, 8KB h-slice exchange via L2 with parity-double-buffered
// mailboxes + sequence-number flags. h redistributed via XOR-swizzled LDS.
// ---------------------------------------------------------------------------
__global__ __launch_bounds__(512, 2) void rnn_rec(
    const float* __restrict__ Whh, const unsigned short* __restrict__ U,
    float* __restrict__ out, unsigned short* __restrict__ hx,
    unsigned int* __restrict__ flags)
{
    const int bx = blockIdx.x;
    const int xcd = bx & 7, slot = bx >> 3;
    if (xcd >= 4) return;                    // 8 working blocks of 16
    const int g = xcd, cu = slot;            // group 0..3, half 0..1
    const int bofs = g * 16, jofs = cu * 256;
    const int tid = threadIdx.x;
    const int w = tid >> 6, l = tid & 63;

    __shared__ unsigned short h_lds[16 * 512];   // 16KB, XOR-swizzled rows

    // Stationary W_hh fragments: wave w covers col tiles (2w) and (2w+1).
    short8 bfr0[16], bfr1[16];
    const int j0 = jofs + (w * 2 + 0) * 16 + (l & 15);
    const int j1 = jofs + (w * 2 + 1) * 16 + (l & 15);
    #pragma unroll
    for (int kc = 0; kc < 16; ++kc) {
        const int k0 = kc * 32 + (l >> 4) * 8;
        {
            const float4 v0 = *reinterpret_cast<const float4*>(Whh + (size_t)j0 * HID + k0);
            const float4 v1 = *reinterpret_cast<const float4*>(Whh + (size_t)j0 * HID + k0 + 4);
            short8 f;
            f[0] = (short)f2bf(v0.x); f[1] = (short)f2bf(v0.y); f[2] = (short)f2bf(v0.z); f[3] = (short)f2bf(v0.w);
            f[4] = (short)f2bf(v1.x); f[5] = (short)f2bf(v1.y); f[6] = (short)f2bf(v1.z); f[7] = (short)f2bf(v1.w);
            bfr0[kc] = f;
        }
        {
            const float4 v0 = *reinterpret_cast<const float4*>(Whh + (size_t)j1 * HID + k0);
            const float4 v1 = *reinterpret_cast<const float4*>(Whh + (size_t)j1 * HID + k0 + 4);
            short8 f;
            f[0] = (short)f2bf(v0.x); f[1] = (short)f2bf(v0.y); f[2] = (short)f2bf(v0.z); f[3] = (short)f2bf(v0.w);
            f[4] = (short)f2bf(v1.x); f[5] = (short)f2bf(v1.y); f[6] = (short)f2bf(v1.z); f[7] = (short)f2bf(v1.w);
            bfr1[kc] = f;
        }
    }

    // h0 = 0
    for (int byte = tid * 16; byte < 16 * 512 * 2; byte += 512 * 16)
        *reinterpret_cast<uint4*>(reinterpret_cast<char*>(h_lds) + byte) = make_uint4(0, 0, 0, 0);

    // U prefetch (one step ahead, registers)
    const int m4 = (l >> 4) * 4;
    unsigned short un0[4], un1[4];
    #pragma unroll
    for (int r = 0; r < 4; ++r) {
        un0[r] = U[((size_t)(bofs + m4 + r)) * HID + j0];
        un1[r] = U[((size_t)(bofs + m4 + r)) * HID + j1];
    }
    __syncthreads();

    const int myflag = g * 2 + cu, pflag = g * 2 + (cu ^ 1);
    unsigned short* hx_own0 = hx + ((size_t)myflag * 2 + 0) * (16 * 256);
    unsigned short* hx_own1 = hx + ((size_t)myflag * 2 + 1) * (16 * 256);
    const unsigned short* hx_peer0 = hx + ((size_t)pflag * 2 + 0) * (16 * 256);
    const unsigned short* hx_peer1 = hx + ((size_t)pflag * 2 + 1) * (16 * 256);
    const int pjofs = (cu ^ 1) * 256;

    const int arow = l & 15;
    const int abase = arow * 1024 + (l >> 4) * 16;
    const int aswz = (arow & 7) << 4;

    for (int t = 0; t < T_STEPS; ++t) {
        unsigned short uc0[4], uc1[4];
        #pragma unroll
        for (int r = 0; r < 4; ++r) { uc0[r] = un0[r]; uc1[r] = un1[r]; }
        if (t + 1 < T_STEPS) {
            #pragma unroll
            for (int r = 0; r < 4; ++r) {
                un0[r] = U[((size_t)(t + 1) * NB + bofs + m4 + r) * HID + j0];
                un1[r] = U[((size_t)(t + 1) * NB + bofs + m4 + r) * HID + j1];
            }
        }

        f32x4 acc0 = {0.f, 0.f, 0.f, 0.f};
        f32x4 acc1 = {0.f, 0.f, 0.f, 0.f};
        #pragma unroll
        for (int kc = 0; kc < 16; ++kc) {
            const int byte = (abase + kc * 64) ^ aswz;
            const short8 a = *reinterpret_cast<const short8*>(reinterpret_cast<const char*>(h_lds) + byte);
            acc0 = __builtin_amdgcn_mfma_f32_16x16x32_bf16(a, bfr0[kc], acc0, 0, 0, 0);
            acc1 = __builtin_amdgcn_mfma_f32_16x16x32_bf16(a, bfr1[kc], acc1, 0, 0, 0);
        }
        __syncthreads();   // all waves done reading h_lds(t)

        float th0[4], th1[4];
        #pragma unroll
        for (int r = 0; r < 4; ++r) {
            const float x0 = acc0[r] + bf2f(uc0[r]);
            th0[r] = 1.f - 2.f / (__expf(2.f * x0) + 1.f);   // exact tanh identity
            const float x1 = acc1[r] + bf2f(uc1[r]);
            th1[r] = 1.f - 2.f / (__expf(2.f * x1) + 1.f);
        }

        if (t == T_STEPS - 1) {
            #pragma unroll
            for (int r = 0; r < 4; ++r) {
                out[(size_t)(bofs + m4 + r) * HID + j0] = th0[r];
                out[(size_t)(bofs + m4 + r) * HID + j1] = th1[r];
            }
            return;
        }

        // publish own new slice: LDS (local) + parity mailbox (peer)
        unsigned short* dst = ((t + 1) & 1) ? hx_own1 : hx_own0;
        const int jl0 = (w * 2 + 0) * 16 + (l & 15);
        const int jl1 = (w * 2 + 1) * 16 + (l & 15);
        #pragma unroll
        for (int r = 0; r < 4; ++r) {
            const int m = m4 + r;
            const unsigned short hb0 = f2bf(th0[r]);
            const unsigned short hb1 = f2bf(th1[r]);
            dst[m * 256 + jl0] = hb0;
            dst[m * 256 + jl1] = hb1;
            const int swz = (m & 7) << 4;
            *reinterpret_cast<unsigned short*>(reinterpret_cast<char*>(h_lds) + ((m * 1024 + (jofs + jl0) * 2) ^ swz)) = hb0;
            *reinterpret_cast<unsigned short*>(reinterpret_cast<char*>(h_lds) + ((m * 1024 + (jofs + jl1) * 2) ^ swz)) = hb1;
        }
        __syncthreads();   // drains each wave's vmem stores (visible at L2)
        if (tid == 0) {
            __threadfence();   // make block's stores agent-visible
            __hip_atomic_store(&flags[myflag], (unsigned)(t + 1), __ATOMIC_RELAXED, __HIP_MEMORY_SCOPE_AGENT);
            while (__hip_atomic_load(&flags[pflag], __ATOMIC_RELAXED, __HIP_MEMORY_SCOPE_AGENT) < (unsigned)(t + 1)) {}
            __threadfence();   // invalidate caches before reading peer data
        }
        __syncthreads();
        {
            const unsigned short* src = ((t + 1) & 1) ? hx_peer1 : hx_peer0;
            const int m = tid >> 5, c8 = (tid & 31) * 8;
            const uint4 v = *reinterpret_cast<const uint4*>(src + m * 256 + c8);
            const int byte = (m * 1024 + (pjofs + c8) * 2) ^ ((m & 7) << 4);
            *reinterpret_cast<uint4*>(reinterpret_cast<char*>(h_lds) + byte) = v;
        }
        __syncthreads();
    }
}

// ---------------------------------------------------------------------------
extern "C" void kernel_launch(void* const* d_in, const int* in_sizes, int n_in,
                              void* d_out, int out_size, void* d_ws, size_t ws_size,
                              hipStream_t stream) {
    const float* X   = (const float*)d_in[0];   // [2048][64][300]
    const float* Wih = (const float*)d_in[1];   // [512][300]
    const float* Whh = (const float*)d_in[2];   // [512][512]
    const float* bih = (const float*)d_in[3];   // [512]
    const float* bhh = (const float*)d_in[4];   // [512]
    float* out = (float*)d_out;                 // [64][512]
    char* ws = (char*)d_ws;
    // ws layout: [0,4KB) flags | [4KB,132KB) h mailboxes | [132KB, +128MB) U bf16
    unsigned int* flags  = (unsigned int*)ws;
    unsigned short* hx   = (unsigned short*)(ws + 4096);
    unsigned short* U    = (unsigned short*)(ws + 4096 + 131072);

    hipMemsetAsync(ws, 0, 4096, stream);   // flags must start at 0 each call
    u_gemm<<<dim3(2048 * 8), dim3(256), 0, stream>>>(X, Wih, bih, bhh, U);
    rnn_rec<<<dim3(16), dim3(512), 0, stream>>>(Whh, U, out, hx, flags);
}